// Round 1
// 761.774 us; speedup vs baseline: 1.2557x; 1.2557x over previous
//
#include <hip/hip_runtime.h>

#define N_PTS 300000
#define DIM 256
#define TM 64
#define HPAD 264   // f16 elements per LDS row (256 + 8 pad)

typedef float  f32x4 __attribute__((ext_vector_type(4)));
typedef _Float16 f16x8 __attribute__((ext_vector_type(8)));
typedef _Float16 f16x4 __attribute__((ext_vector_type(4)));

// ---------------- prep: w2 -> w2T (f16, n-major), lf_w -> lfT (f16, n-major, padded to 32 rows)
__global__ void prep_kernel(const float* __restrict__ w2, const float* __restrict__ lf_w,
                            _Float16* __restrict__ w2T, _Float16* __restrict__ lfT) {
    int i = blockIdx.x * 256 + threadIdx.x;
    if (i < 65536) {
        int n = i >> 8, k = i & 255;
        w2T[n * 256 + k] = (_Float16)w2[k * 256 + n];
    }
    int j = i - 65536;
    if (j >= 0 && j < 32 * 256) {
        int n = j >> 8, k = j & 255;
        lfT[n * 256 + k] = (n < 18) ? (_Float16)lf_w[k * 18 + n] : (_Float16)0.f;
    }
}

// ---------------- fused main kernel: 64 rows per block, 256 threads
__global__ __launch_bounds__(256, 4) void gauss_main(
    const float* __restrict__ mu, const float* __restrict__ scale,
    const float* __restrict__ rot, const float* __restrict__ Q,
    const float* __restrict__ w1, const float* __restrict__ b1,
    const float* __restrict__ gamma_, const float* __restrict__ beta_,
    const float* __restrict__ b2, const float* __restrict__ lf_b,
    const _Float16* __restrict__ w2T, const _Float16* __restrict__ lfT,
    float* __restrict__ out)
{
    __shared__ _Float16 hT[TM * HPAD];   // 33792 B; h (ph1-2), feat f16 (ph3-4a), then staging
    __shared__ float sArr[TM * 20];      // 5120 B; geo staging (ph0-1), lf GEMM result (ph4a-4b)

    float* stage = (float*)hT;           // staging: corners [0,2112) refxy [2112,3520) refxz [3520,4928) refyz [4928,6336)

    const int t    = threadIdx.x;
    const int lane = t & 63;
    const int wid  = t >> 6;            // 0..3
    const int base = blockIdx.x * TM;
    const int l15  = lane & 15;
    const int quad = lane >> 4;
    const int nv   = (N_PTS - base < TM) ? (N_PTS - base) : TM;

    // ---------- Phase 0: stage geo coalesced into sArr (geoS) ----------
    // layout: mu [0,192) floats, scale [192,384), rot [384,640)
    {
        float* geoS = sArr;
        if (nv == TM) {
            if (t < 48)        ((f32x4*)geoS)[t] = ((const f32x4*)(mu    + (size_t)base * 3))[t];
            else if (t < 96)   ((f32x4*)geoS)[t] = ((const f32x4*)(scale + (size_t)base * 3))[t - 48];
            else if (t < 160)  ((f32x4*)geoS)[t] = ((const f32x4*)(rot   + (size_t)base * 4))[t - 96];
        } else {
            for (int i = t; i < 192; i += 256) geoS[i]       = (i < nv * 3) ? mu[(size_t)base * 3 + i]    : 0.f;
            for (int i = t; i < 192; i += 256) geoS[192 + i] = (i < nv * 3) ? scale[(size_t)base * 3 + i] : 0.f;
            for (int i = t; i < 256; i += 256) geoS[384 + i] = (i < nv * 4) ? rot[(size_t)base * 4 + i]   : 0.f;
        }
    }
    __syncthreads();

    // ---------- Phase 1: h = LN(geo@w1 + b1)*gamma+beta, relu -> LDS f16 ----------
    {
        const int c0 = lane * 4;
        float w1r[10][4];
        #pragma unroll
        for (int k = 0; k < 10; k++) {
            f32x4 v = *(const f32x4*)(w1 + k * DIM + c0);
            w1r[k][0] = v[0]; w1r[k][1] = v[1]; w1r[k][2] = v[2]; w1r[k][3] = v[3];
        }
        f32x4 b1v = *(const f32x4*)(b1 + c0);
        f32x4 gv  = *(const f32x4*)(gamma_ + c0);
        f32x4 bv  = *(const f32x4*)(beta_ + c0);

        const float* muS = sArr;
        const float* scS = sArr + 192;
        const float* rtS = sArr + 384;

        for (int i = 0; i < 16; i++) {
            int r = wid * 16 + i;
            float geo[10];
            geo[0] = muS[r*3+0]; geo[1] = muS[r*3+1]; geo[2] = muS[r*3+2];
            geo[3] = scS[r*3+0]; geo[4] = scS[r*3+1]; geo[5] = scS[r*3+2];
            geo[6] = rtS[r*4+0]; geo[7] = rtS[r*4+1]; geo[8] = rtS[r*4+2]; geo[9] = rtS[r*4+3];
            float hv[4];
            #pragma unroll
            for (int cc = 0; cc < 4; cc++) {
                float a = b1v[cc];
                #pragma unroll
                for (int k = 0; k < 10; k++) a = fmaf(geo[k], w1r[k][cc], a);
                hv[cc] = a;
            }
            float s1 = hv[0] + hv[1] + hv[2] + hv[3];
            float s2 = hv[0]*hv[0] + hv[1]*hv[1] + hv[2]*hv[2] + hv[3]*hv[3];
            #pragma unroll
            for (int off = 32; off > 0; off >>= 1) {
                s1 += __shfl_xor(s1, off);
                s2 += __shfl_xor(s2, off);
            }
            float mean = s1 * (1.f / 256.f);
            float var  = s2 * (1.f / 256.f) - mean * mean;
            float rs   = rsqrtf(var + 1e-5f);
            f16x4 p;
            #pragma unroll
            for (int cc = 0; cc < 4; cc++) {
                float x = fmaxf((hv[cc] - mean) * rs * gv[cc] + bv[cc], 0.f);
                p[cc] = (_Float16)x;
            }
            *(f16x4*)(hT + r * HPAD + c0) = p;
        }
    }
    __syncthreads();

    // ---------- Phase 2: E = h @ w2 via MFMA; wave w owns cols [w*64, w*64+64) ----------
    f32x4 acc[4][4] = {};   // [m-tile][n-tile]
    const int n0 = wid * 64;
    {
        const _Float16* bBase = w2T + (size_t)(n0 + l15) * DIM + quad * 8;
        #pragma unroll
        for (int ks = 0; ks < 8; ks++) {
            f16x8 a[4], b[4];
            #pragma unroll
            for (int nt = 0; nt < 4; nt++)
                b[nt] = *(const f16x8*)(bBase + nt * 16 * DIM + ks * 32);
            #pragma unroll
            for (int mt = 0; mt < 4; mt++)
                a[mt] = *(const f16x8*)(hT + (mt * 16 + l15) * HPAD + ks * 32 + quad * 8);
            #pragma unroll
            for (int mt = 0; mt < 4; mt++)
                #pragma unroll
                for (int nt = 0; nt < 4; nt++)
                    acc[mt][nt] = __builtin_amdgcn_mfma_f32_16x16x32_f16(a[mt], b[nt], acc[mt][nt], 0, 0, 0);
        }
    }
    __syncthreads();

    // ---------- Phase 3a: E + b2 -> hT as f16 (MFMA layout) ----------
    {
        float b2v[4];
        #pragma unroll
        for (int nt = 0; nt < 4; nt++) b2v[nt] = b2[n0 + nt * 16 + l15];
        #pragma unroll
        for (int mt = 0; mt < 4; mt++) {
            #pragma unroll
            for (int nt = 0; nt < 4; nt++) {
                #pragma unroll
                for (int reg = 0; reg < 4; reg++) {
                    int r = mt * 16 + quad * 4 + reg;
                    hT[r * HPAD + n0 + nt * 16 + l15] = (_Float16)(acc[mt][nt][reg] + b2v[nt]);
                }
            }
        }
    }
    __syncthreads();

    // ---------- Phase 3b: streaming feat = E + Q -> out (float4) + f16 write-back to hT ----------
    {
        #pragma unroll
        for (int k = 0; k < 16; k++) {
            int idx = k * 256 + t;
            int r   = idx >> 6;            // 0..63, wave-uniform
            int c4  = (idx & 63) << 2;     // float col, 16B aligned
            if (r < nv) {
                f16x4 e  = *(const f16x4*)(hT + r * HPAD + c4);
                f32x4 qv = *(const f32x4*)(Q + (size_t)(base + r) * DIM + c4);
                f32x4 f;
                #pragma unroll
                for (int j = 0; j < 4; j++) f[j] = (float)e[j] + qv[j];
                *(f32x4*)(out + (size_t)(base + r) * DIM + c4) = f;
                f16x4 ff;
                #pragma unroll
                for (int j = 0; j < 4; j++) ff[j] = (_Float16)f[j];
                *(f16x4*)(hT + r * HPAD + c4) = ff;
            }
        }
    }
    __syncthreads();

    // ---------- Phase 4a: s = feat @ lf_w via MFMA (N padded 18->32); wave w owns rows [w*16, w*16+16) ----------
    {
        f32x4 acc2[2] = {};
        const _Float16* lfB = lfT + (size_t)l15 * DIM + quad * 8;
        #pragma unroll
        for (int ks = 0; ks < 8; ks++) {
            f16x8 a   = *(const f16x8*)(hT + (wid * 16 + l15) * HPAD + ks * 32 + quad * 8);
            f16x8 b0  = *(const f16x8*)(lfB + ks * 32);
            f16x8 b1f = *(const f16x8*)(lfB + 16 * DIM + ks * 32);
            acc2[0] = __builtin_amdgcn_mfma_f32_16x16x32_f16(a, b0,  acc2[0], 0, 0, 0);
            acc2[1] = __builtin_amdgcn_mfma_f32_16x16x32_f16(a, b1f, acc2[1], 0, 0, 0);
        }
        #pragma unroll
        for (int tile = 0; tile < 2; tile++) {
            int col = tile * 16 + l15;
            if (col < 18) {
                #pragma unroll
                for (int reg = 0; reg < 4; reg++)
                    sArr[(wid * 16 + quad * 4 + reg) * 20 + col] = acc2[tile][reg];
            }
        }
    }
    __syncthreads();

    // ---------- Phase 4b: per-row geometry -> staging LDS (aliases hT, safe after sync) ----------
    {
        const int row = t >> 2;     // 0..63
        const int q   = t & 3;
        const int g   = base + row;

        float s[18];
        #pragma unroll
        for (int j = 0; j < 18; j++) s[j] = sArr[row * 20 + j] + lf_b[j];

        float hx0 = 0.f, hx1 = 0.f, hx2 = 0.f, mu0 = 0.f, mu1 = 0.f, mu2 = 0.f;
        float qw = 0.f, qx = 0.f, qy = 0.f, qz = 0.f;
        if (g < N_PTS) {
            hx0 = scale[g*3+0] * 0.5f; hx1 = scale[g*3+1] * 0.5f; hx2 = scale[g*3+2] * 0.5f;
            mu0 = mu[g*3+0]; mu1 = mu[g*3+1]; mu2 = mu[g*3+2];
            qw = rot[g*4+0]; qx = rot[g*4+1]; qy = rot[g*4+2]; qz = rot[g*4+3];
        }
        float nrm = fmaxf(sqrtf(qw*qw + qx*qx + qy*qy + qz*qz), 1e-8f);
        float inr = 1.f / nrm;
        qw *= inr; qx *= inr; qy *= inr; qz *= inr;
        float R00 = 1.f - 2.f*(qy*qy + qz*qz), R01 = 2.f*(qx*qy - qz*qw), R02 = 2.f*(qx*qz + qy*qw);
        float R10 = 2.f*(qx*qy + qz*qw), R11 = 1.f - 2.f*(qx*qx + qz*qz), R12 = 2.f*(qy*qz - qx*qw);
        float R20 = 2.f*(qx*qz - qy*qw), R21 = 2.f*(qy*qz + qx*qw), R22 = 1.f - 2.f*(qx*qx + qy*qy);

        const float invXY = 1.0f / 102.400001f;
        const float invZ  = 1.0f / 8.000001f;

        for (int m = q; m < 11; m += 4) {
            float lx, ly, lz;
            if (m == 0)      { lx = 0.f;  ly = 0.f;   lz = 0.f; }
            else if (m == 1) { lx = 0.f;  ly = hx1;   lz = 0.f; }
            else if (m == 2) { lx = 0.f;  ly = -hx1;  lz = 0.f; }
            else if (m == 3) { lx = hx0;  ly = 0.f;   lz = 0.f; }
            else if (m == 4) { lx = -hx0; ly = 0.f;   lz = 0.f; }
            else {
                int mm = m - 5;
                float s0  = 1.f / (1.f + expf(-s[mm*3+0]));
                float s1v = 1.f / (1.f + expf(-s[mm*3+1]));
                float s2v = 1.f / (1.f + expf(-s[mm*3+2]));
                lx = (s0  - 0.5f) * hx0;
                ly = (s1v - 0.5f) * hx1;
                lz = (s2v - 0.5f) * hx2;
            }
            float cx = R00*lx + R01*ly + R02*lz + mu0;
            float cy = R10*lx + R11*ly + R12*lz + mu1;
            float cz = R20*lx + R21*ly + R22*lz + mu2;
            stage[row*33 + m*3 + 0] = cx;
            stage[row*33 + m*3 + 1] = cy;
            stage[row*33 + m*3 + 2] = cz;
            float nx = fminf(fmaxf((cx + 51.2f) * invXY, 0.f), 1.f);
            float ny = fminf(fmaxf((cy + 51.2f) * invXY, 0.f), 1.f);
            float nz = fminf(fmaxf((cz + 5.0f)  * invZ,  0.f), 1.f);
            stage[2112 + row*22 + m*2 + 0] = nx;
            stage[2112 + row*22 + m*2 + 1] = ny;
            stage[3520 + row*22 + m*2 + 0] = nx;
            stage[3520 + row*22 + m*2 + 1] = nz;
            stage[4928 + row*22 + m*2 + 0] = ny;
            stage[4928 + row*22 + m*2 + 1] = nz;
        }
    }
    __syncthreads();

    // ---------- Phase 4c: coalesced float4 copy-out of corners/refs ----------
    {
        const size_t oC  = (size_t)N_PTS * DIM;
        const size_t oXY = oC + (size_t)N_PTS * 33;
        const size_t oXZ = oXY + (size_t)N_PTS * 22;
        const size_t oYZ = oXZ + (size_t)N_PTS * 22;
        float* dC  = out + oC  + (size_t)base * 33;
        float* dXY = out + oXY + (size_t)base * 22;
        float* dXZ = out + oXZ + (size_t)base * 22;
        float* dYZ = out + oYZ + (size_t)base * 22;
        const int cntC = nv * 33, cntR = nv * 22;
        const int vC = cntC >> 2, vR = cntR >> 2;

        f32x4* dC4  = (f32x4*)dC;
        f32x4* dXY4 = (f32x4*)dXY;
        f32x4* dXZ4 = (f32x4*)dXZ;
        f32x4* dYZ4 = (f32x4*)dYZ;
        const f32x4* sC4  = (const f32x4*)(stage);
        const f32x4* sXY4 = (const f32x4*)(stage + 2112);
        const f32x4* sXZ4 = (const f32x4*)(stage + 3520);
        const f32x4* sYZ4 = (const f32x4*)(stage + 4928);

        for (int i = t; i < vC; i += 256) dC4[i]  = sC4[i];
        for (int i = t; i < vR; i += 256) dXY4[i] = sXY4[i];
        for (int i = t; i < vR; i += 256) dXZ4[i] = sXZ4[i];
        for (int i = t; i < vR; i += 256) dYZ4[i] = sYZ4[i];
        // scalar tails (nv*33 / nv*22 are multiples of 4 for nv=64 and nv=32, but stay general)
        for (int i = (vC << 2) + t; i < cntC; i += 256) dC[i]  = stage[i];
        for (int i = (vR << 2) + t; i < cntR; i += 256) dXY[i] = stage[2112 + i];
        for (int i = (vR << 2) + t; i < cntR; i += 256) dXZ[i] = stage[3520 + i];
        for (int i = (vR << 2) + t; i < cntR; i += 256) dYZ[i] = stage[4928 + i];
    }
}

extern "C" void kernel_launch(void* const* d_in, const int* in_sizes, int n_in,
                              void* d_out, int out_size, void* d_ws, size_t ws_size,
                              hipStream_t stream) {
    (void)in_sizes; (void)n_in; (void)out_size; (void)ws_size;
    const float* mu     = (const float*)d_in[0];
    const float* scale  = (const float*)d_in[1];
    const float* rot    = (const float*)d_in[2];
    const float* Q      = (const float*)d_in[3];
    const float* w1     = (const float*)d_in[4];
    const float* b1     = (const float*)d_in[5];
    const float* gamma_ = (const float*)d_in[6];
    const float* beta_  = (const float*)d_in[7];
    const float* w2     = (const float*)d_in[8];
    const float* b2     = (const float*)d_in[9];
    const float* lf_w   = (const float*)d_in[10];
    const float* lf_b   = (const float*)d_in[11];

    _Float16* w2T = (_Float16*)d_ws;
    _Float16* lfT = (_Float16*)((char*)d_ws + 65536 * 2);

    prep_kernel<<<288, 256, 0, stream>>>(w2, lf_w, w2T, lfT);
    gauss_main<<<(N_PTS + TM - 1) / TM, 256, 0, stream>>>(
        mu, scale, rot, Q, w1, b1, gamma_, beta_, b2, lf_b, w2T, lfT, (float*)d_out);
}